// Round 8
// baseline (217.177 us; speedup 1.0000x reference)
//
#include <hip/hip_runtime.h>

#define GRID_N 112
#define O_MAX 48
#define HW_N (GRID_N * GRID_N)   // 12544
#define NT 448                   // 7 wave-private waves; wave w owns row strip w
#define NB 4                     // batches per block: grid 512

typedef _Float16 half8 __attribute__((ext_vector_type(8)));
typedef float    f32x4 __attribute__((ext_vector_type(4)));
typedef float    f32x2 __attribute__((ext_vector_type(2)));

constexpr float INV = 1.0f / (2.0f * 5.0f * 5.0f);  // SIGMA = 5.0

// obj gathers: NO dependence on n (guard is lane-static k+32<O_MAX; values
// past n are masked at use) -> prefetch issues with zero scalar-wait.
__device__ __forceinline__ void gather_oc(const float* __restrict__ ob, int quad,
                                          f32x2* oc0, f32x2* oc1) {
    #pragma unroll
    for (int j = 0; j < 8; ++j) {
        int k = quad * 8 + j;                   // k in [0,32)
        oc0[j] = *(const f32x2*)&ob[k * 2];     // (y,x), always in-bounds
        f32x2 z = {0.f, 0.f};
        oc1[j] = (k + 32 < O_MAX) ? *(const f32x2*)&ob[(k + 32) * 2] : z;
    }
}

__device__ __forceinline__ void load_masks(const int* __restrict__ rm, int h0, int m,
                                           int (*mk)[4]) {
    #pragma unroll
    for (int i = 0; i < 7; ++i) {
        int base = h0 * GRID_N + i * 16 + m;
        #pragma unroll
        for (int r = 0; r < 4; ++r)
            mk[i][r] = rm[base + r * GRID_N];
    }
}

__device__ __forceinline__ void build_a(int n, int ksteps, float fh, float xl, int quad,
                                        const f32x2* oc0, const f32x2* oc1,
                                        half8& a0, half8& a1) {
    #pragma unroll
    for (int j = 0; j < 8; ++j) {
        int k = quad * 8 + j;
        float val = 0.f;
        if (k <= n) {
            float cx = (k < n) ? oc0[j][1] : xl;
            float s  = (k < n) ? -0.5f  : 0.5f;
            float d  = fh - cx;
            val = s * __expf(-d * d * INV);
        }
        a0[j] = (_Float16)val;
    }
    if (ksteps == 2) {
        #pragma unroll
        for (int j = 0; j < 8; ++j) {
            int k = quad * 8 + j + 32;
            float val = 0.f;
            if (k <= n) {
                float cx = (k < n) ? oc1[j][1] : xl;
                float s  = (k < n) ? -0.5f  : 0.5f;
                float d  = fh - cx;
                val = s * __expf(-d * d * INV);
            }
            a1[j] = (_Float16)val;
        }
    }
}

__device__ __forceinline__ void sweep(int n, int ksteps, float yl, int m, int quad, int h0,
                                      const f32x2* oc0, const f32x2* oc1,
                                      half8 a0, half8 a1, const int (*mk)[4],
                                      float* __restrict__ op) {
    #pragma unroll
    for (int tw = 0; tw < 7; ++tw) {
        const float fw = (float)(tw * 16 + m);
        half8 b0;
        #pragma unroll
        for (int j = 0; j < 8; ++j) {
            int k = quad * 8 + j;
            float val = 0.f;
            if (k <= n) {
                float cy = (k < n) ? oc0[j][0] : yl;
                float d  = fw - cy;
                val = __expf(-d * d * INV);
            }
            b0[j] = (_Float16)val;
        }
        f32x4 acc = {0.f, 0.f, 0.f, 0.f};
        acc = __builtin_amdgcn_mfma_f32_16x16x32_f16(a0, b0, acc, 0, 0, 0);
        if (ksteps == 2) {
            half8 b1;
            #pragma unroll
            for (int j = 0; j < 8; ++j) {
                int k = quad * 8 + j + 32;
                float val = 0.f;
                if (k <= n) {
                    float cy = (k < n) ? oc1[j][0] : yl;
                    float d  = fw - cy;
                    val = __expf(-d * d * INV);
                }
                b1[j] = (_Float16)val;
            }
            acc = __builtin_amdgcn_mfma_f32_16x16x32_f16(a1, b1, acc, 0, 0, 0);
        }
        const int w0 = tw * 16 + m;
        #pragma unroll
        for (int r = 0; r < 4; ++r) {
            float v = 0.5f + acc[r];
            v = (mk[tw][r] == 0) ? 0.f : v;
            op[(h0 + r) * GRID_N + w0] = v;
        }
    }
}

// NB=4 batches per wave, pipelined ONE FULL BATCH AHEAD with no LDS and no
// barriers: each iteration issues ALL of batch j+1's loads, then computes
// batch j (whose data has been in flight for an entire batch-compute time).
// vmcnt FIFO: counted waits consume batch-j data while j+1 stays outstanding.
// Per-wave cost: one latency chain + NB x compute (R7 paid the chain per batch).
__global__ __launch_bounds__(NT) void goalmap_kernel(
    const float* __restrict__ xL, const float* __restrict__ yL,
    const float* __restrict__ obj_list, const int* __restrict__ obj_num,
    const int* __restrict__ road_mask, float* __restrict__ out, int B)
{
    const int tid  = threadIdx.x;
    const int lane = tid & 63;
    const int wid  = tid >> 6;                  // 0..6: row strip
    const int m    = lane & 15;
    const int quad = lane >> 4;
    const int h0   = wid * 16 + quad * 4;       // C/D row base
    const float fh = (float)(wid * 16 + m);

    const int b0 = blockIdx.x * NB;

    f32x2 oc0[2][8], oc1[2][8];                 // double-buffered obj coords
    int   mk[2][7][4];                          // double-buffered masks
    int   nS[2]; float xlS[2], ylS[2];          // scalar params

    // ---- prologue: prefetch batch 0 (coords first in FIFO, then masks)
    {
        nS[0] = obj_num[b0]; xlS[0] = xL[b0]; ylS[0] = yL[b0];
        gather_oc(obj_list + (size_t)b0 * (O_MAX * 2), quad, oc0[0], oc1[0]);
        __builtin_amdgcn_sched_barrier(0);
        load_masks(road_mask + (size_t)b0 * HW_N, h0, m, mk[0]);
    }
    __builtin_amdgcn_sched_barrier(0);

    #pragma unroll
    for (int j = 0; j < NB; ++j) {
        const int cur = j & 1;                  // compile-time after unroll
        const int nxt = cur ^ 1;
        const int bj  = b0 + j;

        // ---- (1) issue batch j+1's loads BEFORE computing batch j
        if (j + 1 < NB) {
            const int bn = b0 + j + 1;
            if (bn < B) {
                nS[nxt] = obj_num[bn]; xlS[nxt] = xL[bn]; ylS[nxt] = yL[bn];
                gather_oc(obj_list + (size_t)bn * (O_MAX * 2), quad,
                          oc0[nxt], oc1[nxt]);
                __builtin_amdgcn_sched_barrier(0);
                load_masks(road_mask + (size_t)bn * HW_N, h0, m, mk[nxt]);
            }
        }
        __builtin_amdgcn_sched_barrier(0);

        // ---- (2) compute batch j (data in flight since previous iteration)
        if (bj < B) {
            const int   n  = nS[cur];
            const float xl = xlS[cur], yl = ylS[cur];
            const int ksteps = (n >= 32) ? 2 : 1;

            half8 a0, a1;
            build_a(n, ksteps, fh, xl, quad, oc0[cur], oc1[cur], a0, a1);
            sweep(n, ksteps, yl, m, quad, h0, oc0[cur], oc1[cur], a0, a1,
                  mk[cur], out + (size_t)bj * HW_N);
        }
        __builtin_amdgcn_sched_barrier(0);
    }
}

extern "C" void kernel_launch(void* const* d_in, const int* in_sizes, int n_in,
                              void* d_out, int out_size, void* d_ws, size_t ws_size,
                              hipStream_t stream) {
    const float* xL        = (const float*)d_in[0];
    const float* yL        = (const float*)d_in[1];
    const float* obj_list  = (const float*)d_in[2];
    const int*   obj_num   = (const int*)d_in[3];
    const int*   road_mask = (const int*)d_in[4];
    float*       out       = (float*)d_out;
    const int B = in_sizes[0];  // 2048

    const int grid = (B + NB - 1) / NB;  // 512
    goalmap_kernel<<<grid, NT, 0, stream>>>(xL, yL, obj_list, obj_num, road_mask, out, B);
}